// Round 13
// baseline (24188.388 us; speedup 1.0000x reference)
//
#include <hip/hip_runtime.h>
#include <math.h>

namespace {

constexpr int kNL = 24, kD = 768, kDi = 1536, kN = 16, kR = 48, kK = 4, kV = 50280, kNH = 12;
constexpr int kB = 4, kS = 256;
constexpr int kMtok = kB * kS;   // 1024 token rows
constexpr int kMref = kB * kNL;  // 96 refine rows
constexpr int kVp = 50304;       // kV padded to 128
constexpr int kKa = 3840;        // merged ff2pi K (768 + 3072)
constexpr int kNB = 384;         // persistent grid blocks (64 leaves x 6)

using bf16x8   = __attribute__((ext_vector_type(8))) short;
using f32x4    = __attribute__((ext_vector_type(4))) float;
using ushort8v = __attribute__((ext_vector_type(8))) unsigned short;

__device__ __forceinline__ float siluf(float x) { return x / (1.f + __expf(-x)); }

__device__ __forceinline__ ushort f2b(float f) {
    union { float f; unsigned u; } v; v.f = f;
    unsigned u = v.u;
    unsigned r = (u + 0x7FFFu + ((u >> 16) & 1u)) >> 16;
    return (ushort)r;
}
__device__ __forceinline__ float b2f(ushort u) {
    union { unsigned u; float f; } v; v.u = (unsigned)u << 16; return v.f;
}

#define GLOAD_LDS(g, l) \
    __builtin_amdgcn_global_load_lds((const __attribute__((address_space(1))) void*)(g), \
                                     (__attribute__((address_space(3))) void*)(l), 16, 0, 0)

// ============================================================================
// Generic dispatched GEMM (refine / logits / setup) — unchanged from r12.
// ============================================================================
template <int BM, int BN, int BIAS, int ACT, int RES, int OUTMODE, int PIPE, int SSQ = 0, int SWZ = 0>
__global__ __launch_bounds__(256, (PIPE == 3 ? 3 : 2)) void gemm_bf16(
    const ushort* __restrict__ A, int lda,
    const ushort* __restrict__ B, int ldb,
    float* __restrict__ C, int ldc,
    ushort* __restrict__ Cbf, int ldcb,
    float* __restrict__ C2,
    const float* __restrict__ bias,
    const float* __restrict__ aux,
    const float* __restrict__ aux2,
    int M, int N, int K)
{
    constexpr int ACH = BM / 32;
    constexpr int BCH = BN / 32;
    constexpr int MI  = BM / 32;
    constexpr int NJ  = BN / 32;

    __shared__ ushort As[PIPE][BM * 64];
    __shared__ ushort Bs[PIPE][BN * 64];

    const int tid  = threadIdx.x;
    const int lane = tid & 63;
    const int wave = tid >> 6;
    int bxi = blockIdx.x, byi = blockIdx.y;
    if constexpr (SWZ) {
        int id  = bxi + byi * gridDim.x;
        int swz = (id & 7) * ((gridDim.x * gridDim.y) >> 3) + (id >> 3);
        byi = swz & 7;          // gridDim.y == 8
        bxi = swz >> 3;
    }
    const int m0 = byi * BM;
    const int n0 = bxi * BN;
    const int wr = (wave >> 1) * (BM / 2);
    const int wc = (wave & 1) * (BN / 2);

    f32x4 acc[MI][NJ];
#pragma unroll
    for (int i = 0; i < MI; ++i)
#pragma unroll
        for (int j = 0; j < NJ; ++j) acc[i][j] = f32x4{0.f, 0.f, 0.f, 0.f};

    const int srow = lane >> 3;
    const int scol = ((lane & 7) ^ srow) * 8;
    const ushort* gA[ACH];
    const ushort* gB[BCH];
#pragma unroll
    for (int g = 0; g < ACH; ++g)
        gA[g] = A + (size_t)(m0 + (g * 4 + wave) * 8 + srow) * lda + scol;
#pragma unroll
    for (int g = 0; g < BCH; ++g)
        gB[g] = B + (size_t)(n0 + (g * 4 + wave) * 8 + srow) * ldb + scol;

    const int frow = lane & 15;
    const int kh   = lane >> 4;
    const int nt   = K >> 6;

    auto stage = [&](int t, int buf) {
        const int off = t * 64;
#pragma unroll
        for (int g = 0; g < ACH; ++g) GLOAD_LDS(gA[g] + off, &As[buf][(g * 4 + wave) * 512]);
#pragma unroll
        for (int g = 0; g < BCH; ++g) GLOAD_LDS(gB[g] + off, &Bs[buf][(g * 4 + wave) * 512]);
    };
    auto compute = [&](int buf) {
#pragma unroll
        for (int s = 0; s < 2; ++s) {
            bf16x8 fa[MI], fb[NJ];
#pragma unroll
            for (int i = 0; i < MI; ++i) {
                int r = wr + i * 16 + frow;
                int slot = (s * 4 + kh) ^ (r & 7);
                fa[i] = *(const bf16x8*)&As[buf][r * 64 + slot * 8];
            }
#pragma unroll
            for (int j = 0; j < NJ; ++j) {
                int r = wc + j * 16 + frow;
                int slot = (s * 4 + kh) ^ (r & 7);
                fb[j] = *(const bf16x8*)&Bs[buf][r * 64 + slot * 8];
            }
#pragma unroll
            for (int i = 0; i < MI; ++i)
#pragma unroll
                for (int j = 0; j < NJ; ++j)
                    acc[i][j] = __builtin_amdgcn_mfma_f32_16x16x32_bf16(fa[i], fb[j], acc[i][j], 0, 0, 0);
        }
    };

    if constexpr (PIPE == 3) {
        stage(0, 0);
        if (nt > 1) stage(1, 1);
        for (int t = 0; t < nt; ++t) {
            if (t < nt - 1) {
                asm volatile("s_waitcnt vmcnt(%0)" :: "n"(ACH + BCH) : "memory");
            } else {
                asm volatile("s_waitcnt vmcnt(0)" ::: "memory");
            }
            __builtin_amdgcn_s_barrier();
            if (t + 2 < nt) stage(t + 2, (t + 2) % 3);
            compute(t % 3);
        }
        __builtin_amdgcn_s_barrier();
    } else {
        stage(0, 0);
        __syncthreads();
        int cur = 0;
        for (int t = 0; t < nt; ++t) {
            if (t + 1 < nt) stage(t + 1, cur ^ 1);
            compute(cur);
            __syncthreads();
            cur ^= 1;
        }
    }

    const int ccol = lane & 15;
    const int crow = (lane >> 4) * 4;
    float rsq[MI][4];
    if constexpr (SSQ) {
#pragma unroll
        for (int i = 0; i < MI; ++i)
#pragma unroll
            for (int q = 0; q < 4; ++q) rsq[i][q] = 0.f;
    }
#pragma unroll
    for (int i = 0; i < MI; ++i) {
#pragma unroll
        for (int j = 0; j < NJ; ++j) {
            int gn = n0 + wc + j * 16 + ccol;
            if (gn >= N) continue;
            float bv = BIAS ? bias[gn] : 0.f;
#pragma unroll
            for (int q = 0; q < 4; ++q) {
                int gm = m0 + wr + i * 16 + crow + q;
                if (gm >= M) continue;
                float v = acc[i][j][q] + bv;
                if (ACT == 1) v = fmaxf(v, 0.f) + log1pf(expf(-fabsf(v)));
                if (ACT == 2) v = 0.5f * v * (1.f + erff(v * 0.70710678118654752f));
                if (OUTMODE == 3) {
                    if (gn < 48) Cbf[(size_t)gm * 64 + gn] = f2b(v);
                    else if (gn < 64) { Cbf[(size_t)gm * 64 + gn] = 0; C2[(size_t)(gn - 48) * kMtok + gm] = v; }
                    else if (gn < 80) C2[(size_t)(gn - 48) * kMtok + gm] = v;
                } else if (OUTMODE == 4) {
                    ((ushort*)C2)[(size_t)gn * kMtok + gm] = f2b(v);
                } else if (OUTMODE == 7) {
                    int bb = gm / kNL, ss = gm - bb * kNL;
                    float* stp = C2 + ((size_t)(ss * kB + bb) * kDi + gn) * kN;
                    float a2 = 0.f;
#pragma unroll
                    for (int nn = 0; nn < kN; ++nn) {
                        float sv = stp[nn] + v * aux2[nn];
                        stp[nn] = sv;
                        a2 += sv * aux[nn];
                    }
                    Cbf[(size_t)gm * ldcb + gn] = f2b(a2);
                } else {
                    size_t ci = (size_t)gm * ldc + gn;
                    if (RES) v += C[ci];
                    if (OUTMODE != 2) C[ci] = v;
                    if (OUTMODE == 1 || OUTMODE == 2) Cbf[(size_t)gm * ldcb + gn] = f2b(v);
                    if constexpr (SSQ) rsq[i][q] += v * v;
                }
            }
        }
    }
    if constexpr (SSQ) {
#pragma unroll
        for (int i = 0; i < MI; ++i)
#pragma unroll
            for (int q = 0; q < 4; ++q) {
                rsq[i][q] += __shfl_xor(rsq[i][q], 1, 16);
                rsq[i][q] += __shfl_xor(rsq[i][q], 2, 16);
                rsq[i][q] += __shfl_xor(rsq[i][q], 4, 16);
                rsq[i][q] += __shfl_xor(rsq[i][q], 8, 16);
            }
        float* red = (float*)&As[0][0];
        __syncthreads();
        if ((lane & 15) == 0) {
#pragma unroll
            for (int i = 0; i < MI; ++i)
#pragma unroll
                for (int q = 0; q < 4; ++q) {
                    int rl = (wave >> 1) * 32 + i * 16 + (lane >> 4) * 4 + q;
                    red[(wave & 1) * 64 + rl] = rsq[i][q];
                }
        }
        __syncthreads();
        if (tid < 64) C2[(size_t)blockIdx.x * kMtok + m0 + tid] = red[tid] + red[64 + tid];
    }
}

template <int BM, int BN, int BIAS, int ACT, int RES, int OUTMODE, int PIPE, int SSQ = 0, int SWZ = 0>
static void gemm(const ushort* A, int lda, const ushort* B, int ldb,
                 float* C, int ldc, ushort* Cb, int ldcb, float* C2,
                 const float* bias, const float* aux, int M, int N, int K, hipStream_t s,
                 const float* aux2 = nullptr)
{
    dim3 g((N + BN - 1) / BN, (M + BM - 1) / BM);
    gemm_bf16<BM, BN, BIAS, ACT, RES, OUTMODE, PIPE, SSQ, SWZ><<<g, dim3(256), 0, s>>>(
        A, lda, B, ldb, C, ldc, Cb, ldcb, C2, bias, aux, aux2, M, N, K);
}

// ============================================================================
// Persistent backbone: device tile/unit functions (identical math to r12)
// ============================================================================

__device__ __forceinline__ void compute_pair(const ushort* Asb, const ushort* Bsb,
                                             int wr, int wc, int frow, int kh,
                                             f32x4 (&acc)[2][2])
{
#pragma unroll
    for (int s = 0; s < 2; ++s) {
        bf16x8 fa[2], fb[2];
#pragma unroll
        for (int i = 0; i < 2; ++i) {
            int r = wr + i * 16 + frow;
            int slot = (s * 4 + kh) ^ (r & 7);
            fa[i] = *(const bf16x8*)&Asb[r * 64 + slot * 8];
        }
#pragma unroll
        for (int j = 0; j < 2; ++j) {
            int r = wc + j * 16 + frow;
            int slot = (s * 4 + kh) ^ (r & 7);
            fb[j] = *(const bf16x8*)&Bsb[r * 64 + slot * 8];
        }
#pragma unroll
        for (int i = 0; i < 2; ++i)
#pragma unroll
            for (int j = 0; j < 2; ++j)
                acc[i][j] = __builtin_amdgcn_mfma_f32_16x16x32_bf16(fa[i], fb[j], acc[i][j], 0, 0, 0);
    }
}

// Phase A: rms-normalized in_proj tile (N=3072, K=768)
__device__ void tile_rms(ushort* As, ushort* Bs,
    const float* hbuf, const float* ssq, const float* nw,
    const ushort* Bw, ushort* Xbf, ushort* zTb, int bx, int by)
{
    const int tid  = threadIdx.x;
    const int lane = tid & 63;
    const int wave = tid >> 6;
    const int m0 = by * 64;
    const int n0 = bx * 64;
    const int wr = (wave >> 1) * 32;
    const int wc = (wave & 1) * 32;

    f32x4 acc[2][2];
#pragma unroll
    for (int i = 0; i < 2; ++i)
#pragma unroll
        for (int j = 0; j < 2; ++j) acc[i][j] = f32x4{0.f, 0.f, 0.f, 0.f};

    const int srow = lane >> 3;
    const int scol = ((lane & 7) ^ srow) * 8;
    const ushort* gB[2];
#pragma unroll
    for (int g = 0; g < 2; ++g)
        gB[g] = Bw + (size_t)(n0 + (g * 4 + wave) * 8 + srow) * kD + scol;

    int arow[2];
    float rs[2];
#pragma unroll
    for (int g = 0; g < 2; ++g) {
        arow[g] = m0 + (g * 4 + wave) * 8 + srow;
        float s = 0.f;
#pragma unroll
        for (int c = 0; c < 12; ++c) s += ssq[c * kMtok + arow[g]];
        rs[g] = rsqrtf(s * (1.f / 768.f) + 1e-5f);
    }

    const int frow = lane & 15;
    const int kh   = lane >> 4;

    float4 av[2][2], wv[2];
    auto loadA = [&](int t) {
        int k = t * 64 + scol;
        wv[0] = *(const float4*)&nw[k];
        wv[1] = *(const float4*)&nw[k + 4];
#pragma unroll
        for (int g = 0; g < 2; ++g) {
            av[g][0] = *(const float4*)&hbuf[(size_t)arow[g] * kD + k];
            av[g][1] = *(const float4*)&hbuf[(size_t)arow[g] * kD + k + 4];
        }
    };
    auto writeA = [&](int buf) {
#pragma unroll
        for (int g = 0; g < 2; ++g) {
            ushort8v o;
            o[0] = f2b(av[g][0].x * rs[g] * wv[0].x);
            o[1] = f2b(av[g][0].y * rs[g] * wv[0].y);
            o[2] = f2b(av[g][0].z * rs[g] * wv[0].z);
            o[3] = f2b(av[g][0].w * rs[g] * wv[0].w);
            o[4] = f2b(av[g][1].x * rs[g] * wv[1].x);
            o[5] = f2b(av[g][1].y * rs[g] * wv[1].y);
            o[6] = f2b(av[g][1].z * rs[g] * wv[1].z);
            o[7] = f2b(av[g][1].w * rs[g] * wv[1].w);
            *(ushort8v*)&As[buf * 4096 + (g * 4 + wave) * 512 + lane * 8] = o;
        }
    };
    auto stageB = [&](int t, int buf) {
#pragma unroll
        for (int g = 0; g < 2; ++g)
            GLOAD_LDS(gB[g] + t * 64, &Bs[buf * 4096 + (g * 4 + wave) * 512]);
    };

    loadA(0);
    stageB(0, 0);
    writeA(0);
    __syncthreads();
    int cur = 0;
    for (int t = 0; t < 12; ++t) {
        if (t + 1 < 12) { loadA(t + 1); stageB(t + 1, cur ^ 1); }
        compute_pair(As + cur * 4096, Bs + cur * 4096, wr, wc, frow, kh, acc);
        if (t + 1 < 12) writeA(cur ^ 1);
        __syncthreads();
        cur ^= 1;
    }

    const int ccol = lane & 15;
    const int crow = (lane >> 4) * 4;
#pragma unroll
    for (int i = 0; i < 2; ++i) {
#pragma unroll
        for (int j = 0; j < 2; ++j) {
            int gn = n0 + wc + j * 16 + ccol;
#pragma unroll
            for (int q = 0; q < 4; ++q) {
                int gm = m0 + wr + i * 16 + crow + q;
                float v = acc[i][j][q];
                if (gn < kDi) Xbf[(size_t)gm * kDi + gn] = f2b(v);
                else zTb[(size_t)(gn - kDi) * kMtok + gm] = f2b(siluf(v));
            }
        }
    }
}

// Generic bf16xbf16 tile for phases C (MODE 3), D (MODE 4), F (MODE 0).
template <int MODE>
__device__ void tile_gemm(ushort* As, ushort* Bs,
    const ushort* A, int lda, const ushort* Bw, int ldb,
    float* C, ushort* Cbf, float* C2, const float* bias,
    int K, int bx, int by)
{
    const int tid  = threadIdx.x;
    const int lane = tid & 63;
    const int wave = tid >> 6;
    const int m0 = by * 64;
    const int n0 = bx * 64;
    const int wr = (wave >> 1) * 32;
    const int wc = (wave & 1) * 32;

    f32x4 acc[2][2];
#pragma unroll
    for (int i = 0; i < 2; ++i)
#pragma unroll
        for (int j = 0; j < 2; ++j) acc[i][j] = f32x4{0.f, 0.f, 0.f, 0.f};

    const int srow = lane >> 3;
    const int scol = ((lane & 7) ^ srow) * 8;
    const ushort* gA[2];
    const ushort* gB[2];
#pragma unroll
    for (int g = 0; g < 2; ++g) {
        gA[g] = A  + (size_t)(m0 + (g * 4 + wave) * 8 + srow) * lda + scol;
        gB[g] = Bw + (size_t)(n0 + (g * 4 + wave) * 8 + srow) * ldb + scol;
    }

    const int frow = lane & 15;
    const int kh   = lane >> 4;
    const int nt   = K >> 6;

    auto stage = [&](int t, int buf) {
        const int off = t * 64;
#pragma unroll
        for (int g = 0; g < 2; ++g) {
            GLOAD_LDS(gA[g] + off, &As[buf * 4096 + (g * 4 + wave) * 512]);
            GLOAD_LDS(gB[g] + off, &Bs[buf * 4096 + (g * 4 + wave) * 512]);
        }
    };

    stage(0, 0);
    __syncthreads();
    int cur = 0;
    for (int t = 0; t < nt; ++t) {
        if (t + 1 < nt) stage(t + 1, cur ^ 1);
        compute_pair(As + cur * 4096, Bs + cur * 4096, wr, wc, frow, kh, acc);
        __syncthreads();
        cur ^= 1;
    }

    const int ccol = lane & 15;
    const int crow = (lane >> 4) * 4;
    float rsq[2][4];
    if constexpr (MODE == 0) {
#pragma unroll
        for (int i = 0; i < 2; ++i)
#pragma unroll
            for (int q = 0; q < 4; ++q) rsq[i][q] = 0.f;
    }
#pragma unroll
    for (int i = 0; i < 2; ++i) {
#pragma unroll
        for (int j = 0; j < 2; ++j) {
            int gn = n0 + wc + j * 16 + ccol;
#pragma unroll
            for (int q = 0; q < 4; ++q) {
                int gm = m0 + wr + i * 16 + crow + q;
                float v = acc[i][j][q];
                if constexpr (MODE == 3) {
                    if (gn < 48) Cbf[(size_t)gm * 64 + gn] = f2b(v);
                    else if (gn < 64) { Cbf[(size_t)gm * 64 + gn] = 0; C2[(size_t)(gn - 48) * kMtok + gm] = v; }
                    else if (gn < 80) C2[(size_t)(gn - 48) * kMtok + gm] = v;
                } else if constexpr (MODE == 4) {
                    float w = v + bias[gn];
                    w = fmaxf(w, 0.f) + log1pf(expf(-fabsf(w)));
                    Cbf[(size_t)gn * kMtok + gm] = f2b(w);
                } else {
                    size_t ci = (size_t)gm * kD + gn;
                    v += C[ci];
                    C[ci] = v;
                    rsq[i][q] += v * v;
                }
            }
        }
    }
    if constexpr (MODE == 0) {
#pragma unroll
        for (int i = 0; i < 2; ++i)
#pragma unroll
            for (int q = 0; q < 4; ++q) {
                rsq[i][q] += __shfl_xor(rsq[i][q], 1, 16);
                rsq[i][q] += __shfl_xor(rsq[i][q], 2, 16);
                rsq[i][q] += __shfl_xor(rsq[i][q], 4, 16);
                rsq[i][q] += __shfl_xor(rsq[i][q], 8, 16);
            }
        float* red = (float*)As;
        __syncthreads();
        if ((lane & 15) == 0) {
#pragma unroll
            for (int i = 0; i < 2; ++i)
#pragma unroll
                for (int q = 0; q < 4; ++q) {
                    int rl = (wave >> 1) * 32 + i * 16 + (lane >> 4) * 4 + q;
                    red[(wave & 1) * 64 + rl] = rsq[i][q];
                }
        }
        __syncthreads();
        if (tid < 64) C2[(size_t)bx * kMtok + m0 + tid] = red[tid] + red[64 + tid];
        __syncthreads();
    }
}

// Phase B: conv unit (bx in 0..5, by in 0..63)
__device__ void conv_unit(const ushort* xb, const float* cw, const float* cb,
                          ushort* xc_bf, ushort* xcT, int bx, int by)
{
    int d   = bx * 256 + threadIdx.x;
    int bt0 = by * 16;
    int t0  = bt0 & (kS - 1);
    float w0 = cw[d * 4], w1 = cw[d * 4 + 1], w2 = cw[d * 4 + 2], w3 = cw[d * 4 + 3];
    float bias = cb[d];
    float xv[19];
#pragma unroll
    for (int j = 0; j < 19; ++j) {
        int tt = t0 - 3 + j;
        xv[j] = (tt >= 0) ? b2f(xb[(size_t)(bt0 - 3 + j) * kDi + d]) : 0.f;
    }
    ushort8v o0, o1;
#pragma unroll
    for (int e = 0; e < 16; ++e) {
        float s = bias + xv[e] * w0 + xv[e + 1] * w1 + xv[e + 2] * w2 + xv[e + 3] * w3;
        ushort us = f2b(siluf(s));
        xc_bf[(size_t)(bt0 + e) * kDi + d] = us;
        if (e < 8) o0[e] = us; else o1[e - 8] = us;
    }
    *(ushort8v*)(xcT + (size_t)d * kMtok + bt0)     = o0;
    *(ushort8v*)(xcT + (size_t)d * kMtok + bt0 + 8) = o1;
}

// Phase E: scan unit (u in 0..383)
__device__ void scan_unit(const ushort* dltT, const ushort* xcT, const ushort* zT,
                          const float* bcT, const float* alog, const float* dp,
                          float* states, ushort* y, int u)
{
    int gid = u * 256 + threadIdx.x;
    int n = gid & 15;
    int d = (gid >> 4) % kDi;
    int b = gid / (kDi * kN);
    float Areg = -__expf(alog[d * kN + n]);
    float dpv = dp[d];
    size_t sidx = (size_t)(b * kDi + d) * kN + n;
    float hs = states[sidx];
    const ushort8v* pD = (const ushort8v*)(dltT + (size_t)d * kMtok + b * kS);
    const ushort8v* pX = (const ushort8v*)(xcT  + (size_t)d * kMtok + b * kS);
    const ushort8v* pZ = (const ushort8v*)(zT   + (size_t)d * kMtok + b * kS);
    const float4* pB = (const float4*)(bcT + (size_t)n * kMtok + b * kS);
    const float4* pC = (const float4*)(bcT + (size_t)(16 + n) * kMtok + b * kS);
    ushort8v D = pD[0], X = pX[0], Z = pZ[0];
    float4 B0 = pB[0], B1 = pB[1], C0 = pC[0], C1 = pC[1];
    ushort* yrow = y + (size_t)(b * kS) * kDi + d;
    for (int g = 0; g < kS / 8; ++g) {
        ushort8v Dn, Xn, Zn; float4 Bn0, Bn1, Cn0, Cn1;
        if (g + 1 < kS / 8) {
            Dn = pD[g + 1]; Xn = pX[g + 1]; Zn = pZ[g + 1];
            Bn0 = pB[2 * g + 2]; Bn1 = pB[2 * g + 3];
            Cn0 = pC[2 * g + 2]; Cn1 = pC[2 * g + 3];
        }
#pragma unroll
        for (int e = 0; e < 8; ++e) {
            float dv = b2f(D[e]), xv = b2f(X[e]), zv = b2f(Z[e]);
            float Bv = (e < 4) ? (&B0.x)[e] : (&B1.x)[e - 4];
            float Cv = (e < 4) ? (&C0.x)[e] : (&C1.x)[e - 4];
            hs = __expf(dv * Areg) * hs + (dv * xv) * Bv;
            float p = hs * Cv;
            p += __shfl_xor(p, 1, 16);
            p += __shfl_xor(p, 2, 16);
            p += __shfl_xor(p, 4, 16);
            p += __shfl_xor(p, 8, 16);
            if (n == 0) yrow[(size_t)(g * 8 + e) * kDi] = f2b((p + xv * dpv) * zv);
        }
        D = Dn; X = Xn; Z = Zn; B0 = Bn0; B1 = Bn1; C0 = Cn0; C1 = Cn1;
    }
    states[sidx] = hs;
}

// Software grid barrier: 64 leaves x 6 blocks, accumulating counters.
__device__ __forceinline__ void gbar(int* leaf, int* root, int* gen)
{
    __syncthreads();
    if (threadIdx.x == 0) {
        __threadfence();
        int g = __hip_atomic_load(gen, __ATOMIC_RELAXED, __HIP_MEMORY_SCOPE_AGENT);
        int a = atomicAdd(&leaf[(blockIdx.x & 63) << 5], 1) + 1;
        if (a == (g + 1) * (kNB / 64)) {
            int r = atomicAdd(root, 1) + 1;
            if (r == (g + 1) * 64)
                __hip_atomic_fetch_add(gen, 1, __ATOMIC_RELEASE, __HIP_MEMORY_SCOPE_AGENT);
        }
        while (__hip_atomic_load(gen, __ATOMIC_ACQUIRE, __HIP_MEMORY_SCOPE_AGENT) == g)
            __builtin_amdgcn_s_sleep(2);
        __threadfence();
    }
    __syncthreads();
}

// Persistent backbone pass: 24 layers x {rms+in_proj, conv, x_proj, dt, scan, out_proj}
__global__ __launch_bounds__(256, 2) void backbone_kernel(
    float* h, float* ssqp, const float* norm_w,
    const ushort* ipw_all, ushort* x_bf, ushort* zT_b,
    const float* cw, const float* cb, ushort* xc_bf, ushort* xcT_b,
    const ushort* xpw_bf, ushort* dtin_bf, float* bcT,
    const ushort* dpw_bf, const float* dpb, ushort* dltT_b,
    const float* alog, const float* dpp, float* st, ushort* yb_bf,
    const ushort* opw_all,
    int* leaf, int* root, int* gen, int pass)
{
    __shared__ ushort lds[4 * 4096];   // 32 KB: As = lds[0..2), Bs = lds[2..4)
    ushort* As = lds;
    ushort* Bs = lds + 2 * 4096;
    const int nb = gridDim.x;

    for (int l = 0; l < kNL; ++l) {
        const ushort* ipw_l = ipw_all + (size_t)l * 2 * kDi * kD;
        const ushort* opw_l = opw_all + (size_t)l * kD * kDi;
        const ushort* xpw_l = xpw_bf + (size_t)l * 128 * kDi;
        const ushort* dpw_l = dpw_bf + (size_t)l * kDi * 64;
        const float* nw_l  = norm_w + (size_t)l * kD;
        const float* cw_l  = cw + (size_t)l * kDi * kK;
        const float* cb_l  = cb + (size_t)l * kDi;
        const float* dpb_l = dpb + (size_t)l * kDi;
        const float* alog_l = alog + (size_t)l * kDi * kN;
        const float* dpp_l  = dpp + (size_t)l * kDi;
        float* st_l = st + (size_t)l * kB * kDi * kN;

        for (int t = blockIdx.x; t < 768; t += nb)
            tile_rms(As, Bs, h, ssqp, nw_l, ipw_l, x_bf, zT_b, t % 48, t / 48);
        gbar(leaf, root, gen);
        for (int u = blockIdx.x; u < 384; u += nb)
            conv_unit(x_bf, cw_l, cb_l, xc_bf, xcT_b, u % 6, u / 6);
        gbar(leaf, root, gen);
        for (int t = blockIdx.x; t < 32; t += nb)
            tile_gemm<3>(As, Bs, xc_bf, kDi, xpw_l, kDi, nullptr, dtin_bf, bcT, nullptr,
                         kDi, t % 2, t / 2);
        gbar(leaf, root, gen);
        for (int t = blockIdx.x; t < 384; t += nb)
            tile_gemm<4>(As, Bs, dtin_bf, 64, dpw_l, 64, nullptr, dltT_b, nullptr, dpb_l,
                         64, t % 24, t / 24);
        gbar(leaf, root, gen);
        for (int u = blockIdx.x; u < 384; u += nb)
            scan_unit(dltT_b, xcT_b, zT_b, bcT, alog_l, dpp_l, st_l, yb_bf, u);
        gbar(leaf, root, gen);
        if (!(pass == 0 && l == kNL - 1)) {
            for (int t = blockIdx.x; t < 192; t += nb)
                tile_gemm<0>(As, Bs, yb_bf, kDi, opw_l, kDi, h, nullptr, ssqp, nullptr,
                             kDi, t % 12, t / 12);
            if (l < kNL - 1) gbar(leaf, root, gen);
        }
    }
}

// ============================================================================
// Fallback per-layer kernels (r12) + glue kernels
// ============================================================================
__global__ __launch_bounds__(256, 4) void gemm_rms(
    const float* __restrict__ hbuf, const float* __restrict__ ssq,
    const float* __restrict__ nw,
    const ushort* __restrict__ B, int ldb,
    ushort* __restrict__ Xbf, ushort* __restrict__ zTb,
    int M, int N, int K)
{
    __shared__ ushort As[2][64 * 64];
    __shared__ ushort Bs[2][64 * 64];
    tile_rms(&As[0][0], &Bs[0][0], hbuf, ssq, nw, B, Xbf, zTb, blockIdx.x, blockIdx.y);
}

__global__ void conv_kernel(
    const ushort* __restrict__ xb, const float* __restrict__ cw,
    const float* __restrict__ cb, ushort* __restrict__ xc_bf,
    ushort* __restrict__ xcT)
{
    conv_unit(xb, cw, cb, xc_bf, xcT, blockIdx.x, blockIdx.y);
}

__global__ __launch_bounds__(256) void scan_kernel(
    const ushort* __restrict__ dltT, const ushort* __restrict__ xcT,
    const ushort* __restrict__ zT, const float* __restrict__ bcT,
    const float* __restrict__ alog, const float* __restrict__ dp,
    float* __restrict__ states, ushort* __restrict__ y)
{
    scan_unit(dltT, xcT, zT, bcT, alog, dp, states, y, blockIdx.x);
}

__global__ void cvt_kernel(const float* __restrict__ src, ushort* __restrict__ dst, int n) {
    int i = (blockIdx.x * 256 + threadIdx.x) * 4;
    if (i >= n) return;
    float4 v = *(const float4*)(src + i);
    ushort4 o; o.x = f2b(v.x); o.y = f2b(v.y); o.z = f2b(v.z); o.w = f2b(v.w);
    *(ushort4*)(dst + i) = o;
}

__global__ void cvt_xpw_kernel(const float* __restrict__ src, ushort* __restrict__ dst) {
    int i = (blockIdx.x * 256 + threadIdx.x) * 4;
    if (i >= 24 * 80 * 1536) return;
    int l = i / (80 * 1536), r = i - l * (80 * 1536);
    int row = r / 1536, col = r - row * 1536;
    float4 v = *(const float4*)(src + i);
    ushort4 o; o.x = f2b(v.x); o.y = f2b(v.y); o.z = f2b(v.z); o.w = f2b(v.w);
    *(ushort4*)(dst + ((size_t)(l * 128 + row)) * 1536 + col) = o;
}

__global__ void cvt_dpw_kernel(const float* __restrict__ src, ushort* __restrict__ dst) {
    int i = blockIdx.x * 256 + threadIdx.x;
    if (i >= 24 * 1536 * 64) return;
    int col = i & 63, row = i >> 6;
    dst[i] = (col < 48) ? f2b(src[(size_t)row * 48 + col]) : (ushort)0;
}

__global__ void cvt_ff2T_kernel(const float* __restrict__ src, ushort* __restrict__ dst) {
    int i = blockIdx.x * 256 + threadIdx.x;
    if (i >= 768 * 3072) return;
    int d = i / 3072, f = i - d * 3072;
    dst[(size_t)f * 768 + d] = f2b(src[i]);
}

__global__ void cvt_pi_kernel(const float* __restrict__ src, ushort* __restrict__ dst) {
    int i = blockIdx.x * 256 + threadIdx.x;
    if (i >= 1536 * 768) return;
    int o = i / 768, d = i - o * 768;
    dst[(size_t)o * kKa + d] = f2b(src[i]);
}

__global__ void pib_kernel(const float* __restrict__ piw, const float* __restrict__ ff2b,
                           float* __restrict__ bias2) {
    int o = blockIdx.x * 256 + threadIdx.x;
    if (o >= 1536) return;
    float s = 0.f;
    for (int d = 0; d < 768; ++d) s += piw[(size_t)o * 768 + d] * ff2b[d];
    bias2[o] = s;
}

__global__ void embed_kernel(const int* __restrict__ ids, const int* __restrict__ msk,
                             const float* __restrict__ embed, float* __restrict__ h,
                             float* __restrict__ ssq)
{
    int i = blockIdx.x * 256 + threadIdx.x;
    int row = i / kD, col = i - row * kD;
    float v = embed[(size_t)ids[row] * kD + col] * (float)msk[row];
    h[i] = v;
    float s = v * v;
    s += __shfl_xor(s, 1);  s += __shfl_xor(s, 2);  s += __shfl_xor(s, 4);
    s += __shfl_xor(s, 8);  s += __shfl_xor(s, 16); s += __shfl_xor(s, 32);
    if ((threadIdx.x & 63) == 0) ssq[(col >> 6) * kMtok + row] = s;
}

__global__ __launch_bounds__(256) void rms_kernel(const float* __restrict__ x,
                                                  const float* __restrict__ w,
                                                  ushort* __restrict__ out)
{
    __shared__ float red[256];
    int row = blockIdx.x, tid = threadIdx.x;
    const float* xr = x + (size_t)row * kD;
    float s = 0.f;
    for (int j = tid; j < kD; j += 256) { float v = xr[j]; s += v * v; }
    red[tid] = s; __syncthreads();
    for (int o = 128; o > 0; o >>= 1) { if (tid < o) red[tid] += red[tid + o]; __syncthreads(); }
    float rs = rsqrtf(red[0] / (float)kD + 1e-5f);
    for (int j = tid; j < kD; j += 256) out[(size_t)row * kD + j] = f2b(xr[j] * rs * w[j]);
}

__global__ __launch_bounds__(256) void ln_kernel(const float* __restrict__ x,
                                                 const float* __restrict__ w,
                                                 const float* __restrict__ b,
                                                 ushort* __restrict__ out)
{
    __shared__ float r1[256], r2[256];
    int row = blockIdx.x, tid = threadIdx.x;
    const float* xr = x + (size_t)row * kD;
    float s = 0.f, s2 = 0.f;
    for (int j = tid; j < kD; j += 256) { float v = xr[j]; s += v; s2 += v * v; }
    r1[tid] = s; r2[tid] = s2; __syncthreads();
    for (int o = 128; o > 0; o >>= 1) {
        if (tid < o) { r1[tid] += r1[tid + o]; r2[tid] += r2[tid + o]; }
        __syncthreads();
    }
    float mean = r1[0] / (float)kD;
    float var = r2[0] / (float)kD - mean * mean;
    float rsv = rsqrtf(var + 1e-5f);
    for (int j = tid; j < kD; j += 256)
        out[(size_t)row * kD + j] = f2b((xr[j] - mean) * rsv * w[j] + b[j]);
}

__global__ void contract_kernel(const float* __restrict__ st, const float* __restrict__ Cw,
                                ushort* __restrict__ dDi)
{
    int i = blockIdx.x * 256 + threadIdx.x;
    int row = i / kDi, di = i - row * kDi;
    int b = row / kNL, s = row - b * kNL;
    const float* sp = st + ((size_t)(s * kB + b) * kDi + di) * kN;
    float acc = 0.f;
#pragma unroll
    for (int nn = 0; nn < kN; ++nn) acc += sp[nn] * Cw[nn];
    dDi[i] = f2b(acc);
}

__global__ __launch_bounds__(32) void attn_kernel(const float* __restrict__ qkv,
                                                  ushort* __restrict__ o)
{
    int b = blockIdx.x / kNH;
    int hh = blockIdx.x - b * kNH;
    int sq = threadIdx.x;
    if (sq >= kNL) return;
    const float* qrow = qkv + (size_t)(b * kNL + sq) * (3 * kD) + hh * 64;
    float q[64];
#pragma unroll
    for (int e = 0; e < 64; ++e) q[e] = qrow[e];
    float sc[kNL];
    float mx = -1e30f;
    for (int sk = 0; sk < kNL; ++sk) {
        const float* krow = qkv + (size_t)(b * kNL + sk) * (3 * kD) + kD + hh * 64;
        float dt = 0.f;
#pragma unroll
        for (int e = 0; e < 64; ++e) dt += q[e] * krow[e];
        dt *= 0.125f;
        sc[sk] = dt;
        mx = fmaxf(mx, dt);
    }
    float sum = 0.f;
    for (int sk = 0; sk < kNL; ++sk) { sc[sk] = expf(sc[sk] - mx); sum += sc[sk]; }
    float inv = 1.f / sum;
    float out[64];
#pragma unroll
    for (int e = 0; e < 64; ++e) out[e] = 0.f;
    for (int sk = 0; sk < kNL; ++sk) {
        float wgt = sc[sk] * inv;
        const float* vrow = qkv + (size_t)(b * kNL + sk) * (3 * kD) + 2 * kD + hh * 64;
#pragma unroll
        for (int e = 0; e < 64; ++e) out[e] += wgt * vrow[e];
    }
    ushort* orow = o + (size_t)(b * kNL + sq) * kD + hh * 64;
#pragma unroll
    for (int e = 0; e < 64; ++e) orow[e] = f2b(out[e]);
}

} // namespace

extern "C" void kernel_launch(void* const* d_in, const int* in_sizes, int n_in,
                              void* d_out, int out_size, void* d_ws, size_t ws_size,
                              hipStream_t stream)
{
    const int*   q_ids  = (const int*)d_in[0];
    const int*   q_msk  = (const int*)d_in[1];
    const int*   a_ids  = (const int*)d_in[2];
    const int*   a_msk  = (const int*)d_in[3];
    const float* embed  = (const float*)d_in[4];
    const float* norm_w = (const float*)d_in[5];
    const float* ipw    = (const float*)d_in[6];
    const float* cw     = (const float*)d_in[7];
    const float* cb     = (const float*)d_in[8];
    const float* xpw    = (const float*)d_in[9];
    const float* dpw    = (const float*)d_in[10];
    const float* dpb    = (const float*)d_in[11];
    const float* alog   = (const float*)d_in[12];
    const float* dpp    = (const float*)d_in[13];
    const float* opw    = (const float*)d_in[14];
    const float* norm_f = (const float*)d_in[15];
    const float* ln1w   = (const float*)d_in[16];
    const float* ln1b   = (const float*)d_in[17];
    const float* qkvw   = (const float*)d_in[18];
    const float* qkvbi  = (const float*)d_in[19];
    const float* aow    = (const float*)d_in[20];
    const float* aob    = (const float*)d_in[21];
    const float* ln2w   = (const float*)d_in[22];
    const float* ln2b   = (const float*)d_in[23];
    const float* ff1w   = (const float*)d_in[24];
    const float* ff1b   = (const float*)d_in[25];
    const float* ff2w   = (const float*)d_in[26];
    const float* ff2b   = (const float*)d_in[27];
    const float* Cwp    = (const float*)d_in[28];
    const float* powp   = (const float*)d_in[29];
    const float* Bwp    = (const float*)d_in[30];
    const float* piwp   = (const float*)d_in[31];

    // ---- workspace arena ----
    char* base = (char*)d_ws;
    size_t cur = 0;
    auto allocB = [&](size_t bytes) { char* p = base + cur; cur = (cur + bytes + 255) & ~(size_t)255; return p; };
    auto allocF = [&](size_t n) { return (float*)allocB(n * 4); };
    auto allocH = [&](size_t n) { return (ushort*)allocB(n * 2); };

    // fp32
    float* h     = allocF((size_t)kMtok * kD);
    float* ssqp  = allocF((size_t)12 * kMtok);
    float* bcT   = allocF((size_t)32 * kMtok);
    float* st    = allocF((size_t)kNL * kB * kDi * kN);
    float* x768  = allocF((size_t)kMref * kD);
    float* qkvB  = allocF((size_t)kMref * 3 * kD);
    float* bias2 = allocF((size_t)kDi);
    int*   barp  = (int*)allocB((2048 + 64) * 4);     // 64 leaves*32 + root + gen
    // bf16 activations
    ushort* x_bf    = allocH((size_t)kMtok * kDi);
    ushort* zT_b    = allocH((size_t)kDi * kMtok);
    ushort* xcT_b   = allocH((size_t)kDi * kMtok);
    ushort* dltT_b  = allocH((size_t)kDi * kMtok);
    ushort* xc_bf   = allocH((size_t)kMtok * kDi);
    ushort* dtin_bf = allocH((size_t)kMtok * 64);
    ushort* yb_bf   = allocH((size_t)kMtok * kDi);
    ushort* xin_bf  = allocH((size_t)kMtok * kD);
    ushort* dDi_bf  = allocH((size_t)128 * kDi);
    ushort* tb_bf   = allocH((size_t)128 * kD);
    ushort* o768_bf = allocH((size_t)128 * kD);
    ushort* A2      = allocH((size_t)128 * kKa);
    // bf16 weights
    ushort* xpw_bf  = allocH((size_t)kNL * 128 * kDi);
    ushort* dpw_bf  = allocH((size_t)kNL * kDi * 64);
    ushort* powp_bf = allocH((size_t)kD * kDi);
    ushort* qkvw_bf = allocH((size_t)3 * kD * kD);
    ushort* aow_bf  = allocH((size_t)kD * kD);
    ushort* ff1w_bf = allocH((size_t)4 * kD * kD);
    ushort* ff2wT   = allocH((size_t)4 * kD * kD);
    ushort* piw_bf  = allocH((size_t)kDi * kD);
    ushort* B2      = allocH((size_t)kDi * kKa);
    ushort* emb_bf  = allocH((size_t)kVp * kD);

    size_t base_end = cur;
    ushort* ipw_all = allocH((size_t)kNL * 2 * kDi * kD);
    ushort* opw_all = allocH((size_t)kNL * kD * kDi);
    bool full = (cur <= ws_size);
    ushort* ipw_stg = nullptr;
    ushort* opw_stg = nullptr;
    if (!full) {
        cur = base_end;
        ipw_stg = allocH((size_t)2 * kDi * kD);
        opw_stg = allocH((size_t)kD * kDi);
        if (cur > ws_size) return;
    }

    auto cvt = [&](const float* s, ushort* d, size_t n) {
        cvt_kernel<<<dim3((unsigned)((n / 4 + 255) / 256)), dim3(256), 0, stream>>>(s, d, (int)n);
    };

    hipMemsetAsync(st, 0, sizeof(float) * (size_t)kNL * kB * kDi * kN, stream);
    hipMemsetAsync(barp, 0, (2048 + 64) * 4, stream);

    cvt_xpw_kernel<<<dim3(2880), dim3(256), 0, stream>>>(xpw, xpw_bf);
    cvt_dpw_kernel<<<dim3(9216), dim3(256), 0, stream>>>(dpw, dpw_bf);
    cvt(powp, powp_bf, (size_t)kD * kDi);
    cvt(qkvw, qkvw_bf, (size_t)3 * kD * kD);
    cvt(aow,  aow_bf,  (size_t)kD * kD);
    cvt(ff1w, ff1w_bf, (size_t)4 * kD * kD);
    cvt(piwp, piw_bf,  (size_t)kDi * kD);
    cvt_ff2T_kernel<<<dim3(9216), dim3(256), 0, stream>>>(ff2w, ff2wT);
    cvt_pi_kernel<<<dim3(4608), dim3(256), 0, stream>>>(piwp, B2);
    pib_kernel<<<dim3(6), dim3(256), 0, stream>>>(piwp, ff2b, bias2);
    gemm<64, 64, 0, 0, 0, 2, 3>(piw_bf, kD, ff2wT, kD, nullptr, 0, B2 + kD, kKa, nullptr,
                                nullptr, nullptr, kDi, 4 * kD, kD, stream);
    cvt(embed, emb_bf, (size_t)kV * kD);
    if (full) {
        cvt(ipw, ipw_all, (size_t)kNL * 2 * kDi * kD);
        cvt(opw, opw_all, (size_t)kNL * kD * kDi);
    }

    int* leaf = barp;
    int* root = barp + 2048;
    int* gen  = barp + 2048 + 32;

    for (int pass = 0; pass < 2; ++pass) {
        const int* ids = pass ? a_ids : q_ids;
        const int* msk = pass ? a_msk : q_msk;

        embed_kernel<<<dim3(kMtok * kD / 256), dim3(256), 0, stream>>>(ids, msk, embed, h, ssqp);

        if (full) {
            backbone_kernel<<<dim3(kNB), dim3(256), 0, stream>>>(
                h, ssqp, norm_w, ipw_all, x_bf, zT_b, cw, cb, xc_bf, xcT_b,
                xpw_bf, dtin_bf, bcT, dpw_bf, dpb, dltT_b, alog, dpp, st, yb_bf,
                opw_all, leaf, root, gen, pass);
        } else {
            for (int l = 0; l < kNL; ++l) {
                cvt(ipw + (size_t)l * 2 * kDi * kD, ipw_stg, (size_t)2 * kDi * kD);
                cvt(opw + (size_t)l * kD * kDi, opw_stg, (size_t)kD * kDi);
                gemm_rms<<<dim3(48, 16), dim3(256), 0, stream>>>(
                    h, ssqp, norm_w + (size_t)l * kD, ipw_stg, kD, x_bf, zT_b, kMtok, 2 * kDi, kD);
                conv_kernel<<<dim3(kDi / 256, kMtok / 16), dim3(256), 0, stream>>>(
                    x_bf, cw + (size_t)l * kDi * kK, cb + (size_t)l * kDi, xc_bf, xcT_b);
                gemm<64, 64, 0, 0, 0, 3, 3>(xc_bf, kDi, xpw_bf + (size_t)l * 128 * kDi, kDi,
                                            nullptr, 0, dtin_bf, 0, bcT,
                                            nullptr, nullptr, kMtok, 128, kDi, stream);
                gemm<64, 64, 1, 1, 0, 4, 3>(dtin_bf, 64, dpw_bf + (size_t)l * kDi * 64, 64,
                                            nullptr, 0, nullptr, 0, (float*)dltT_b,
                                            dpb + (size_t)l * kDi, nullptr, kMtok, kDi, 64, stream);
                scan_kernel<<<dim3(kB * kDi * kN / 256), dim3(256), 0, stream>>>(
                    dltT_b, xcT_b, zT_b, bcT, alog + (size_t)l * kDi * kN, dpp + (size_t)l * kDi,
                    st + (size_t)l * kB * kDi * kN, yb_bf);
                if (!(pass == 0 && l == kNL - 1)) {
                    gemm<64, 64, 0, 0, 1, 0, 3, 1>(yb_bf, kDi, opw_stg, kDi, h, kD, nullptr, 0, ssqp,
                                                   nullptr, nullptr, kMtok, kD, kDi, stream);
                }
            }
        }

        if (pass == 0) {
            contract_kernel<<<dim3(kMref * kDi / 256), dim3(256), 0, stream>>>(st, Cwp, dDi_bf);
            for (int it = 0; it < 12; ++it) {
                gemm<64, 64, 0, 0, 0, 0, 3>(dDi_bf, kDi, powp_bf, kDi, x768, kD, nullptr, 0, nullptr,
                                            nullptr, nullptr, kMref, kD, kDi, stream);
                ln_kernel<<<dim3(kMref), dim3(256), 0, stream>>>(x768, ln1w, ln1b, tb_bf);
                gemm<64, 64, 1, 0, 0, 0, 3>(tb_bf, kD, qkvw_bf, kD, qkvB, 3 * kD, nullptr, 0, nullptr,
                                            qkvbi, nullptr, kMref, 3 * kD, kD, stream);
                attn_kernel<<<dim3(kB * kNH), dim3(32), 0, stream>>>(qkvB, o768_bf);
                gemm<64, 64, 1, 0, 1, 1, 3>(o768_bf, kD, aow_bf, kD, x768, kD, A2, kKa, nullptr,
                                            aob, nullptr, kMref, kD, kD, stream);
                ln_kernel<<<dim3(kMref), dim3(256), 0, stream>>>(x768, ln2w, ln2b, tb_bf);
                gemm<64, 64, 1, 2, 0, 2, 3>(tb_bf, kD, ff1w_bf, kD, nullptr, 0, A2 + kD, kKa, nullptr,
                                            ff1b, nullptr, kMref, 4 * kD, kD, stream);
                gemm<64, 64, 1, 0, 0, 7, 3>(A2, kKa, B2, kKa, nullptr, 0, dDi_bf, kDi, st,
                                            bias2, Cwp, kMref, kDi, kKa, stream, Bwp);
            }
        } else {
            rms_kernel<<<dim3(kMtok), dim3(256), 0, stream>>>(h, norm_f, xin_bf);
            gemm<128, 128, 0, 0, 0, 0, 2, 0, 1>(xin_bf, kD, emb_bf, kD, (float*)d_out, kV,
                                                nullptr, 0, nullptr,
                                                nullptr, nullptr, kMtok, kV, kD, stream);
        }
    }
}

// Round 14
// 8681.142 us; speedup vs baseline: 2.7863x; 2.7863x over previous
//
#include <hip/hip_runtime.h>
#include <math.h>

namespace {

constexpr int kNL = 24, kD = 768, kDi = 1536, kN = 16, kR = 48, kK = 4, kV = 50280, kNH = 12;
constexpr int kB = 4, kS = 256;
constexpr int kMtok = kB * kS;   // 1024 token rows
constexpr int kMref = kB * kNL;  // 96 refine rows
constexpr int kVp = 50304;       // kV padded to 128
constexpr int kKa = 3840;        // merged ff2pi K (768 + 3072)

using bf16x8   = __attribute__((ext_vector_type(8))) short;
using f32x4    = __attribute__((ext_vector_type(4))) float;
using ushort8v = __attribute__((ext_vector_type(8))) unsigned short;

__device__ __forceinline__ float siluf(float x) { return x / (1.f + __expf(-x)); }

__device__ __forceinline__ ushort f2b(float f) {
    union { float f; unsigned u; } v; v.f = f;
    unsigned u = v.u;
    unsigned r = (u + 0x7FFFu + ((u >> 16) & 1u)) >> 16;
    return (ushort)r;
}
__device__ __forceinline__ float b2f(ushort u) {
    union { unsigned u; float f; } v; v.u = (unsigned)u << 16; return v.f;
}

#define GLOAD_LDS(g, l) \
    __builtin_amdgcn_global_load_lds((const __attribute__((address_space(1))) void*)(g), \
                                     (__attribute__((address_space(3))) void*)(l), 16, 0, 0)

// ---------------- bf16 MFMA GEMM: C[M,N] = A[M,K] @ B[N,K]^T ----------------
// PIPE=3: 3-buffer LDS, counted vmcnt + raw s_barrier. PIPE=2: 2-buffer.
// ACT: 0 none, 1 softplus, 2 gelu(exact).
// OUTMODE:
//  0 fp32 C (+RES)     1 fp32 C + bf16 Cbf     2 bf16 Cbf only
//  3 x_proj: gn<48 -> dt-in bf16 (Cbf, ld 64; cols 48..63 zeroed);
//            gn in [48,80) -> C2[(gn-48)*1024+gm] fp32 (bc^T)
//  4 dt:     ((ushort*)C2)[gn*1024+gm] = bf16(v)   (dlt^T, ACT applied)
//  7 merged-pi + state update: v += bias[gn] (BIAS=1, =bias2);
//    st (C2) += v*aux2[nn]; dDi (Cbf) = dot(st, aux)
// SSQ=1: C2[bx*1024 + row] = row partial sum of v^2 (RMS path)
// SWZ=1: XCD-grouped by-fastest block swizzle (nwg%8==0, gridDim.y==8)
template <int BM, int BN, int BIAS, int ACT, int RES, int OUTMODE, int PIPE, int SSQ = 0, int SWZ = 0>
__global__ __launch_bounds__(256, (PIPE == 3 ? 3 : 2)) void gemm_bf16(
    const ushort* __restrict__ A, int lda,
    const ushort* __restrict__ B, int ldb,
    float* __restrict__ C, int ldc,
    ushort* __restrict__ Cbf, int ldcb,
    float* __restrict__ C2,
    const float* __restrict__ bias,
    const float* __restrict__ aux,
    const float* __restrict__ aux2,
    int M, int N, int K)
{
    constexpr int ACH = BM / 32;
    constexpr int BCH = BN / 32;
    constexpr int MI  = BM / 32;
    constexpr int NJ  = BN / 32;

    __shared__ ushort As[PIPE][BM * 64];
    __shared__ ushort Bs[PIPE][BN * 64];

    const int tid  = threadIdx.x;
    const int lane = tid & 63;
    const int wave = tid >> 6;
    int bxi = blockIdx.x, byi = blockIdx.y;
    if constexpr (SWZ) {
        int id  = bxi + byi * gridDim.x;
        int swz = (id & 7) * ((gridDim.x * gridDim.y) >> 3) + (id >> 3);
        byi = swz & 7;          // gridDim.y == 8
        bxi = swz >> 3;
    }
    const int m0 = byi * BM;
    const int n0 = bxi * BN;
    const int wr = (wave >> 1) * (BM / 2);
    const int wc = (wave & 1) * (BN / 2);

    f32x4 acc[MI][NJ];
#pragma unroll
    for (int i = 0; i < MI; ++i)
#pragma unroll
        for (int j = 0; j < NJ; ++j) acc[i][j] = f32x4{0.f, 0.f, 0.f, 0.f};

    const int srow = lane >> 3;
    const int scol = ((lane & 7) ^ srow) * 8;
    const ushort* gA[ACH];
    const ushort* gB[BCH];
#pragma unroll
    for (int g = 0; g < ACH; ++g)
        gA[g] = A + (size_t)(m0 + (g * 4 + wave) * 8 + srow) * lda + scol;
#pragma unroll
    for (int g = 0; g < BCH; ++g)
        gB[g] = B + (size_t)(n0 + (g * 4 + wave) * 8 + srow) * ldb + scol;

    const int frow = lane & 15;
    const int kh   = lane >> 4;
    const int nt   = K >> 6;

    auto stage = [&](int t, int buf) {
        const int off = t * 64;
#pragma unroll
        for (int g = 0; g < ACH; ++g) GLOAD_LDS(gA[g] + off, &As[buf][(g * 4 + wave) * 512]);
#pragma unroll
        for (int g = 0; g < BCH; ++g) GLOAD_LDS(gB[g] + off, &Bs[buf][(g * 4 + wave) * 512]);
    };
    auto compute = [&](int buf) {
#pragma unroll
        for (int s = 0; s < 2; ++s) {
            bf16x8 fa[MI], fb[NJ];
#pragma unroll
            for (int i = 0; i < MI; ++i) {
                int r = wr + i * 16 + frow;
                int slot = (s * 4 + kh) ^ (r & 7);
                fa[i] = *(const bf16x8*)&As[buf][r * 64 + slot * 8];
            }
#pragma unroll
            for (int j = 0; j < NJ; ++j) {
                int r = wc + j * 16 + frow;
                int slot = (s * 4 + kh) ^ (r & 7);
                fb[j] = *(const bf16x8*)&Bs[buf][r * 64 + slot * 8];
            }
#pragma unroll
            for (int i = 0; i < MI; ++i)
#pragma unroll
                for (int j = 0; j < NJ; ++j)
                    acc[i][j] = __builtin_amdgcn_mfma_f32_16x16x32_bf16(fa[i], fb[j], acc[i][j], 0, 0, 0);
        }
    };

    if constexpr (PIPE == 3) {
        stage(0, 0);
        if (nt > 1) stage(1, 1);
        for (int t = 0; t < nt; ++t) {
            if (t < nt - 1) {
                asm volatile("s_waitcnt vmcnt(%0)" :: "n"(ACH + BCH) : "memory");
            } else {
                asm volatile("s_waitcnt vmcnt(0)" ::: "memory");
            }
            __builtin_amdgcn_s_barrier();
            if (t + 2 < nt) stage(t + 2, (t + 2) % 3);
            compute(t % 3);
        }
        __builtin_amdgcn_s_barrier();
    } else {
        stage(0, 0);
        __syncthreads();
        int cur = 0;
        for (int t = 0; t < nt; ++t) {
            if (t + 1 < nt) stage(t + 1, cur ^ 1);
            compute(cur);
            __syncthreads();
            cur ^= 1;
        }
    }

    const int ccol = lane & 15;
    const int crow = (lane >> 4) * 4;
    float rsq[MI][4];
    if constexpr (SSQ) {
#pragma unroll
        for (int i = 0; i < MI; ++i)
#pragma unroll
            for (int q = 0; q < 4; ++q) rsq[i][q] = 0.f;
    }
#pragma unroll
    for (int i = 0; i < MI; ++i) {
#pragma unroll
        for (int j = 0; j < NJ; ++j) {
            int gn = n0 + wc + j * 16 + ccol;
            if (gn >= N) continue;
            float bv = BIAS ? bias[gn] : 0.f;
#pragma unroll
            for (int q = 0; q < 4; ++q) {
                int gm = m0 + wr + i * 16 + crow + q;
                if (gm >= M) continue;
                float v = acc[i][j][q] + bv;
                if (ACT == 1) v = fmaxf(v, 0.f) + log1pf(expf(-fabsf(v)));
                if (ACT == 2) v = 0.5f * v * (1.f + erff(v * 0.70710678118654752f));
                if (OUTMODE == 3) {
                    if (gn < 48) Cbf[(size_t)gm * 64 + gn] = f2b(v);
                    else if (gn < 64) { Cbf[(size_t)gm * 64 + gn] = 0; C2[(size_t)(gn - 48) * kMtok + gm] = v; }
                    else if (gn < 80) C2[(size_t)(gn - 48) * kMtok + gm] = v;
                } else if (OUTMODE == 4) {
                    ((ushort*)C2)[(size_t)gn * kMtok + gm] = f2b(v);
                } else if (OUTMODE == 7) {
                    int bb = gm / kNL, ss = gm - bb * kNL;
                    float* stp = C2 + ((size_t)(ss * kB + bb) * kDi + gn) * kN;
                    float a2 = 0.f;
#pragma unroll
                    for (int nn = 0; nn < kN; ++nn) {
                        float sv = stp[nn] + v * aux2[nn];
                        stp[nn] = sv;
                        a2 += sv * aux[nn];
                    }
                    Cbf[(size_t)gm * ldcb + gn] = f2b(a2);
                } else {
                    size_t ci = (size_t)gm * ldc + gn;
                    if (RES) v += C[ci];
                    if (OUTMODE != 2) C[ci] = v;
                    if (OUTMODE == 1 || OUTMODE == 2) Cbf[(size_t)gm * ldcb + gn] = f2b(v);
                    if constexpr (SSQ) rsq[i][q] += v * v;
                }
            }
        }
    }
    if constexpr (SSQ) {
#pragma unroll
        for (int i = 0; i < MI; ++i)
#pragma unroll
            for (int q = 0; q < 4; ++q) {
                rsq[i][q] += __shfl_xor(rsq[i][q], 1, 16);
                rsq[i][q] += __shfl_xor(rsq[i][q], 2, 16);
                rsq[i][q] += __shfl_xor(rsq[i][q], 4, 16);
                rsq[i][q] += __shfl_xor(rsq[i][q], 8, 16);
            }
        float* red = (float*)&As[0][0];   // 128 floats scratch
        __syncthreads();
        if ((lane & 15) == 0) {
#pragma unroll
            for (int i = 0; i < MI; ++i)
#pragma unroll
                for (int q = 0; q < 4; ++q) {
                    int rl = (wave >> 1) * 32 + i * 16 + (lane >> 4) * 4 + q;
                    red[(wave & 1) * 64 + rl] = rsq[i][q];
                }
        }
        __syncthreads();
        if (tid < 64) C2[(size_t)blockIdx.x * kMtok + m0 + tid] = red[tid] + red[64 + tid];
    }
}

template <int BM, int BN, int BIAS, int ACT, int RES, int OUTMODE, int PIPE, int SSQ = 0, int SWZ = 0>
static void gemm(const ushort* A, int lda, const ushort* B, int ldb,
                 float* C, int ldc, ushort* Cb, int ldcb, float* C2,
                 const float* bias, const float* aux, int M, int N, int K, hipStream_t s,
                 const float* aux2 = nullptr)
{
    dim3 g((N + BN - 1) / BN, (M + BM - 1) / BM);
    gemm_bf16<BM, BN, BIAS, ACT, RES, OUTMODE, PIPE, SSQ, SWZ><<<g, dim3(256), 0, s>>>(
        A, lda, B, ldb, C, ldc, Cb, ldcb, C2, bias, aux, aux2, M, N, K);
}

// ------- in_proj with fused RMSNorm (reg-staged A) --------------------------
__global__ __launch_bounds__(256, 4) void gemm_rms(
    const float* __restrict__ hbuf, const float* __restrict__ ssq,
    const float* __restrict__ nw,
    const ushort* __restrict__ B, int ldb,
    ushort* __restrict__ Xbf, ushort* __restrict__ zTb,
    int M, int N, int K)
{
    constexpr int MI = 2, NJ = 2, BCH = 2;
    __shared__ ushort As[2][64 * 64];
    __shared__ ushort Bs[2][64 * 64];
    const int tid  = threadIdx.x;
    const int lane = tid & 63;
    const int wave = tid >> 6;
    const int m0 = blockIdx.y * 64;
    const int n0 = blockIdx.x * 64;
    const int wr = (wave >> 1) * 32;
    const int wc = (wave & 1) * 32;

    f32x4 acc[MI][NJ];
#pragma unroll
    for (int i = 0; i < MI; ++i)
#pragma unroll
        for (int j = 0; j < NJ; ++j) acc[i][j] = f32x4{0.f, 0.f, 0.f, 0.f};

    const int srow = lane >> 3;
    const int scol = ((lane & 7) ^ srow) * 8;
    const ushort* gB[BCH];
#pragma unroll
    for (int g = 0; g < BCH; ++g)
        gB[g] = B + (size_t)(n0 + (g * 4 + wave) * 8 + srow) * ldb + scol;

    int arow[2];
    float rs[2];
#pragma unroll
    for (int g = 0; g < 2; ++g) {
        arow[g] = m0 + (g * 4 + wave) * 8 + srow;
        float s = 0.f;
#pragma unroll
        for (int c = 0; c < 12; ++c) s += ssq[c * kMtok + arow[g]];
        rs[g] = rsqrtf(s * (1.f / 768.f) + 1e-5f);
    }

    const int frow = lane & 15;
    const int kh   = lane >> 4;
    const int nt   = K >> 6;

    float4 av[2][2], wv[2];
    auto loadA = [&](int t) {
        int k = t * 64 + scol;
        wv[0] = *(const float4*)&nw[k];
        wv[1] = *(const float4*)&nw[k + 4];
#pragma unroll
        for (int g = 0; g < 2; ++g) {
            av[g][0] = *(const float4*)&hbuf[(size_t)arow[g] * K + k];
            av[g][1] = *(const float4*)&hbuf[(size_t)arow[g] * K + k + 4];
        }
    };
    auto writeA = [&](int buf) {
#pragma unroll
        for (int g = 0; g < 2; ++g) {
            ushort8v o;
            o[0] = f2b(av[g][0].x * rs[g] * wv[0].x);
            o[1] = f2b(av[g][0].y * rs[g] * wv[0].y);
            o[2] = f2b(av[g][0].z * rs[g] * wv[0].z);
            o[3] = f2b(av[g][0].w * rs[g] * wv[0].w);
            o[4] = f2b(av[g][1].x * rs[g] * wv[1].x);
            o[5] = f2b(av[g][1].y * rs[g] * wv[1].y);
            o[6] = f2b(av[g][1].z * rs[g] * wv[1].z);
            o[7] = f2b(av[g][1].w * rs[g] * wv[1].w);
            *(ushort8v*)&As[buf][(g * 4 + wave) * 512 + lane * 8] = o;
        }
    };
    auto stageB = [&](int t, int buf) {
#pragma unroll
        for (int g = 0; g < BCH; ++g) GLOAD_LDS(gB[g] + t * 64, &Bs[buf][(g * 4 + wave) * 512]);
    };
    auto compute = [&](int buf) {
#pragma unroll
        for (int s = 0; s < 2; ++s) {
            bf16x8 fa[MI], fb[NJ];
#pragma unroll
            for (int i = 0; i < MI; ++i) {
                int r = wr + i * 16 + frow;
                int slot = (s * 4 + kh) ^ (r & 7);
                fa[i] = *(const bf16x8*)&As[buf][r * 64 + slot * 8];
            }
#pragma unroll
            for (int j = 0; j < NJ; ++j) {
                int r = wc + j * 16 + frow;
                int slot = (s * 4 + kh) ^ (r & 7);
                fb[j] = *(const bf16x8*)&Bs[buf][r * 64 + slot * 8];
            }
#pragma unroll
            for (int i = 0; i < MI; ++i)
#pragma unroll
                for (int j = 0; j < NJ; ++j)
                    acc[i][j] = __builtin_amdgcn_mfma_f32_16x16x32_bf16(fa[i], fb[j], acc[i][j], 0, 0, 0);
        }
    };

    loadA(0);
    stageB(0, 0);
    writeA(0);
    __syncthreads();
    int cur = 0;
    for (int t = 0; t < nt; ++t) {
        if (t + 1 < nt) { loadA(t + 1); stageB(t + 1, cur ^ 1); }
        compute(cur);
        if (t + 1 < nt) writeA(cur ^ 1);
        __syncthreads();
        cur ^= 1;
    }

    const int ccol = lane & 15;
    const int crow = (lane >> 4) * 4;
#pragma unroll
    for (int i = 0; i < MI; ++i) {
#pragma unroll
        for (int j = 0; j < NJ; ++j) {
            int gn = n0 + wc + j * 16 + ccol;
#pragma unroll
            for (int q = 0; q < 4; ++q) {
                int gm = m0 + wr + i * 16 + crow + q;
                float v = acc[i][j][q];
                if (gn < kDi) Xbf[(size_t)gm * kDi + gn] = f2b(v);
                else zTb[(size_t)(gn - kDi) * kMtok + gm] = f2b(siluf(v));
            }
        }
    }
}

// ---------------- conversions ----------------
__global__ void cvt_kernel(const float* __restrict__ src, ushort* __restrict__ dst, int n) {
    int i = (blockIdx.x * 256 + threadIdx.x) * 4;
    if (i >= n) return;
    float4 v = *(const float4*)(src + i);
    ushort4 o; o.x = f2b(v.x); o.y = f2b(v.y); o.z = f2b(v.z); o.w = f2b(v.w);
    *(ushort4*)(dst + i) = o;
}

// xpw [24][80][1536] -> padded [24][128][1536]
__global__ void cvt_xpw_kernel(const float* __restrict__ src, ushort* __restrict__ dst) {
    int i = (blockIdx.x * 256 + threadIdx.x) * 4;
    if (i >= 24 * 80 * 1536) return;
    int l = i / (80 * 1536), r = i - l * (80 * 1536);
    int row = r / 1536, col = r - row * 1536;
    float4 v = *(const float4*)(src + i);
    ushort4 o; o.x = f2b(v.x); o.y = f2b(v.y); o.z = f2b(v.z); o.w = f2b(v.w);
    *(ushort4*)(dst + ((size_t)(l * 128 + row)) * 1536 + col) = o;
}

// dpw [24][1536][48] -> padded [24][1536][64] (K-pad zero)
__global__ void cvt_dpw_kernel(const float* __restrict__ src, ushort* __restrict__ dst) {
    int i = blockIdx.x * 256 + threadIdx.x;
    if (i >= 24 * 1536 * 64) return;
    int col = i & 63, row = i >> 6;
    dst[i] = (col < 48) ? f2b(src[(size_t)row * 48 + col]) : (ushort)0;
}

// ff2w [768][3072] -> transposed bf16 [3072][768]
__global__ void cvt_ff2T_kernel(const float* __restrict__ src, ushort* __restrict__ dst) {
    int i = blockIdx.x * 256 + threadIdx.x;
    if (i >= 768 * 3072) return;
    int d = i / 3072, f = i - d * 3072;
    dst[(size_t)f * 768 + d] = f2b(src[i]);
}

// piw [1536][768] fp32 -> B2 cols 0..767 (ld 3840) bf16
__global__ void cvt_pi_kernel(const float* __restrict__ src, ushort* __restrict__ dst) {
    int i = blockIdx.x * 256 + threadIdx.x;
    if (i >= 1536 * 768) return;
    int o = i / 768, d = i - o * 768;
    dst[(size_t)o * kKa + d] = f2b(src[i]);
}

// bias2[o] = sum_d piw[o][d] * ff2b[d]
__global__ void pib_kernel(const float* __restrict__ piw, const float* __restrict__ ff2b,
                           float* __restrict__ bias2) {
    int o = blockIdx.x * 256 + threadIdx.x;
    if (o >= 1536) return;
    float s = 0.f;
    for (int d = 0; d < 768; ++d) s += piw[(size_t)o * 768 + d] * ff2b[d];
    bias2[o] = s;
}

// ---------------- embedding (+ ssq_part init) ----------------
__global__ void embed_kernel(const int* __restrict__ ids, const int* __restrict__ msk,
                             const float* __restrict__ embed, float* __restrict__ h,
                             float* __restrict__ ssq)
{
    int i = blockIdx.x * 256 + threadIdx.x;
    int row = i / kD, col = i - row * kD;
    float v = embed[(size_t)ids[row] * kD + col] * (float)msk[row];
    h[i] = v;
    float s = v * v;
    s += __shfl_xor(s, 1);  s += __shfl_xor(s, 2);  s += __shfl_xor(s, 4);
    s += __shfl_xor(s, 8);  s += __shfl_xor(s, 16); s += __shfl_xor(s, 32);
    if ((threadIdx.x & 63) == 0) ssq[(col >> 6) * kMtok + row] = s;
}

// ---------------- RMSNorm -> bf16 (final norm before logits only) ---------
__global__ __launch_bounds__(256) void rms_kernel(const float* __restrict__ x,
                                                  const float* __restrict__ w,
                                                  ushort* __restrict__ out)
{
    __shared__ float red[256];
    int row = blockIdx.x, tid = threadIdx.x;
    const float* xr = x + (size_t)row * kD;
    float s = 0.f;
    for (int j = tid; j < kD; j += 256) { float v = xr[j]; s += v * v; }
    red[tid] = s; __syncthreads();
    for (int o = 128; o > 0; o >>= 1) { if (tid < o) red[tid] += red[tid + o]; __syncthreads(); }
    float rs = rsqrtf(red[0] / (float)kD + 1e-5f);
    for (int j = tid; j < kD; j += 256) out[(size_t)row * kD + j] = f2b(xr[j] * rs * w[j]);
}

// ---------------- LayerNorm -> bf16 ----------------
__global__ __launch_bounds__(256) void ln_kernel(const float* __restrict__ x,
                                                 const float* __restrict__ w,
                                                 const float* __restrict__ b,
                                                 ushort* __restrict__ out)
{
    __shared__ float r1[256], r2[256];
    int row = blockIdx.x, tid = threadIdx.x;
    const float* xr = x + (size_t)row * kD;
    float s = 0.f, s2 = 0.f;
    for (int j = tid; j < kD; j += 256) { float v = xr[j]; s += v; s2 += v * v; }
    r1[tid] = s; r2[tid] = s2; __syncthreads();
    for (int o = 128; o > 0; o >>= 1) {
        if (tid < o) { r1[tid] += r1[tid + o]; r2[tid] += r2[tid + o]; }
        __syncthreads();
    }
    float mean = r1[0] / (float)kD;
    float var = r2[0] / (float)kD - mean * mean;
    float rsv = rsqrtf(var + 1e-5f);
    for (int j = tid; j < kD; j += 256)
        out[(size_t)row * kD + j] = f2b((xr[j] - mean) * rsv * w[j] + b[j]);
}

// ---------------- causal conv (K=4) + bias + silu (bf16 in/out) ------------
__global__ __launch_bounds__(256) void conv_kernel(
    const ushort* __restrict__ xb, const float* __restrict__ cw,
    const float* __restrict__ cb, ushort* __restrict__ xc_bf,
    ushort* __restrict__ xcT)
{
    int d   = blockIdx.x * 256 + threadIdx.x;
    int bt0 = blockIdx.y * 16;
    int t0  = bt0 & (kS - 1);
    float w0 = cw[d * 4], w1 = cw[d * 4 + 1], w2 = cw[d * 4 + 2], w3 = cw[d * 4 + 3];
    float bias = cb[d];
    float xv[19];
#pragma unroll
    for (int j = 0; j < 19; ++j) {
        int tt = t0 - 3 + j;
        xv[j] = (tt >= 0) ? b2f(xb[(size_t)(bt0 - 3 + j) * kDi + d]) : 0.f;
    }
    ushort8v o0, o1;
#pragma unroll
    for (int e = 0; e < 16; ++e) {
        float s = bias + xv[e] * w0 + xv[e + 1] * w1 + xv[e + 2] * w2 + xv[e + 3] * w3;
        ushort us = f2b(siluf(s));
        xc_bf[(size_t)(bt0 + e) * kDi + d] = us;
        if (e < 8) o0[e] = us; else o1[e - 8] = us;
    }
    *(ushort8v*)(xcT + (size_t)d * kMtok + bt0)     = o0;
    *(ushort8v*)(xcT + (size_t)d * kMtok + bt0 + 8) = o1;
}

// ---------------- selective scan + gating ----------------
__global__ __launch_bounds__(256) void scan_kernel(
    const ushort* __restrict__ dltT, const ushort* __restrict__ xcT,
    const ushort* __restrict__ zT, const float* __restrict__ bcT,
    const float* __restrict__ alog, const float* __restrict__ dp,
    float* __restrict__ states, ushort* __restrict__ y)
{
    int gid = blockIdx.x * 256 + threadIdx.x;
    int n = gid & 15;
    int d = (gid >> 4) % kDi;
    int b = gid / (kDi * kN);
    float Areg = -__expf(alog[d * kN + n]);
    float dpv = dp[d];
    size_t sidx = (size_t)(b * kDi + d) * kN + n;
    float hs = states[sidx];
    const ushort8v* pD = (const ushort8v*)(dltT + (size_t)d * kMtok + b * kS);
    const ushort8v* pX = (const ushort8v*)(xcT  + (size_t)d * kMtok + b * kS);
    const ushort8v* pZ = (const ushort8v*)(zT   + (size_t)d * kMtok + b * kS);
    const float4* pB = (const float4*)(bcT + (size_t)n * kMtok + b * kS);
    const float4* pC = (const float4*)(bcT + (size_t)(16 + n) * kMtok + b * kS);
    ushort8v D = pD[0], X = pX[0], Z = pZ[0];
    float4 B0 = pB[0], B1 = pB[1], C0 = pC[0], C1 = pC[1];
    ushort* yrow = y + (size_t)(b * kS) * kDi + d;
    for (int g = 0; g < kS / 8; ++g) {
        ushort8v Dn, Xn, Zn; float4 Bn0, Bn1, Cn0, Cn1;
        if (g + 1 < kS / 8) {
            Dn = pD[g + 1]; Xn = pX[g + 1]; Zn = pZ[g + 1];
            Bn0 = pB[2 * g + 2]; Bn1 = pB[2 * g + 3];
            Cn0 = pC[2 * g + 2]; Cn1 = pC[2 * g + 3];
        }
#pragma unroll
        for (int e = 0; e < 8; ++e) {
            float dv = b2f(D[e]), xv = b2f(X[e]), zv = b2f(Z[e]);
            float Bv = (e < 4) ? (&B0.x)[e] : (&B1.x)[e - 4];
            float Cv = (e < 4) ? (&C0.x)[e] : (&C1.x)[e - 4];
            hs = __expf(dv * Areg) * hs + (dv * xv) * Bv;
            float p = hs * Cv;
            p += __shfl_xor(p, 1, 16);
            p += __shfl_xor(p, 2, 16);
            p += __shfl_xor(p, 4, 16);
            p += __shfl_xor(p, 8, 16);
            if (n == 0) yrow[(size_t)(g * 8 + e) * kDi] = f2b((p + xv * dpv) * zv);
        }
        D = Dn; X = Xn; Z = Zn; B0 = Bn0; B1 = Bn1; C0 = Cn0; C1 = Cn1;
    }
    states[sidx] = hs;
}

// ---------------- refine: initial d = states . C_w -> bf16 ----------------
__global__ void contract_kernel(const float* __restrict__ st, const float* __restrict__ Cw,
                                ushort* __restrict__ dDi)
{
    int i = blockIdx.x * 256 + threadIdx.x;
    int row = i / kDi, di = i - row * kDi;
    int b = row / kNL, s = row - b * kNL;
    const float* sp = st + ((size_t)(s * kB + b) * kDi + di) * kN;
    float acc = 0.f;
#pragma unroll
    for (int nn = 0; nn < kN; ++nn) acc += sp[nn] * Cw[nn];
    dDi[i] = f2b(acc);
}

// ---------------- tiny attention -> bf16 ----------------
__global__ __launch_bounds__(32) void attn_kernel(const float* __restrict__ qkv,
                                                  ushort* __restrict__ o)
{
    int b = blockIdx.x / kNH;
    int hh = blockIdx.x - b * kNH;
    int sq = threadIdx.x;
    if (sq >= kNL) return;
    const float* qrow = qkv + (size_t)(b * kNL + sq) * (3 * kD) + hh * 64;
    float q[64];
#pragma unroll
    for (int e = 0; e < 64; ++e) q[e] = qrow[e];
    float sc[kNL];
    float mx = -1e30f;
    for (int sk = 0; sk < kNL; ++sk) {
        const float* krow = qkv + (size_t)(b * kNL + sk) * (3 * kD) + kD + hh * 64;
        float dt = 0.f;
#pragma unroll
        for (int e = 0; e < 64; ++e) dt += q[e] * krow[e];
        dt *= 0.125f;
        sc[sk] = dt;
        mx = fmaxf(mx, dt);
    }
    float sum = 0.f;
    for (int sk = 0; sk < kNL; ++sk) { sc[sk] = expf(sc[sk] - mx); sum += sc[sk]; }
    float inv = 1.f / sum;
    float out[64];
#pragma unroll
    for (int e = 0; e < 64; ++e) out[e] = 0.f;
    for (int sk = 0; sk < kNL; ++sk) {
        float wgt = sc[sk] * inv;
        const float* vrow = qkv + (size_t)(b * kNL + sk) * (3 * kD) + 2 * kD + hh * 64;
#pragma unroll
        for (int e = 0; e < 64; ++e) out[e] += wgt * vrow[e];
    }
    ushort* orow = o + (size_t)(b * kNL + sq) * kD + hh * 64;
#pragma unroll
    for (int e = 0; e < 64; ++e) orow[e] = f2b(out[e]);
}

} // namespace

extern "C" void kernel_launch(void* const* d_in, const int* in_sizes, int n_in,
                              void* d_out, int out_size, void* d_ws, size_t ws_size,
                              hipStream_t stream)
{
    const int*   q_ids  = (const int*)d_in[0];
    const int*   q_msk  = (const int*)d_in[1];
    const int*   a_ids  = (const int*)d_in[2];
    const int*   a_msk  = (const int*)d_in[3];
    const float* embed  = (const float*)d_in[4];
    const float* norm_w = (const float*)d_in[5];
    const float* ipw    = (const float*)d_in[6];
    const float* cw     = (const float*)d_in[7];
    const float* cb     = (const float*)d_in[8];
    const float* xpw    = (const float*)d_in[9];
    const float* dpw    = (const float*)d_in[10];
    const float* dpb    = (const float*)d_in[11];
    const float* alog   = (const float*)d_in[12];
    const float* dpp    = (const float*)d_in[13];
    const float* opw    = (const float*)d_in[14];
    const float* norm_f = (const float*)d_in[15];
    const float* ln1w   = (const float*)d_in[16];
    const float* ln1b   = (const float*)d_in[17];
    const float* qkvw   = (const float*)d_in[18];
    const float* qkvbi  = (const float*)d_in[19];
    const float* aow    = (const float*)d_in[20];
    const float* aob    = (const float*)d_in[21];
    const float* ln2w   = (const float*)d_in[22];
    const float* ln2b   = (const float*)d_in[23];
    const float* ff1w   = (const float*)d_in[24];
    const float* ff1b   = (const float*)d_in[25];
    const float* ff2w   = (const float*)d_in[26];
    const float* ff2b   = (const float*)d_in[27];
    const float* Cwp    = (const float*)d_in[28];
    const float* powp   = (const float*)d_in[29];
    const float* Bwp    = (const float*)d_in[30];
    const float* piwp   = (const float*)d_in[31];

    // ---- workspace arena ----
    char* base = (char*)d_ws;
    size_t cur = 0;
    auto allocB = [&](size_t bytes) { char* p = base + cur; cur = (cur + bytes + 255) & ~(size_t)255; return p; };
    auto allocF = [&](size_t n) { return (float*)allocB(n * 4); };
    auto allocH = [&](size_t n) { return (ushort*)allocB(n * 2); };

    // fp32
    float* h     = allocF((size_t)kMtok * kD);
    float* ssqp  = allocF((size_t)12 * kMtok);
    float* bcT   = allocF((size_t)32 * kMtok);
    float* st    = allocF((size_t)kNL * kB * kDi * kN);
    float* x768  = allocF((size_t)kMref * kD);
    float* qkvB  = allocF((size_t)kMref * 3 * kD);
    float* bias2 = allocF((size_t)kDi);
    // bf16 activations
    ushort* x_bf    = allocH((size_t)kMtok * kDi);
    ushort* zT_b    = allocH((size_t)kDi * kMtok);
    ushort* xcT_b   = allocH((size_t)kDi * kMtok);
    ushort* dltT_b  = allocH((size_t)kDi * kMtok);
    ushort* xc_bf   = allocH((size_t)kMtok * kDi);
    ushort* dtin_bf = allocH((size_t)kMtok * 64);
    ushort* yb_bf   = allocH((size_t)kMtok * kDi);
    ushort* xin_bf  = allocH((size_t)kMtok * kD);
    ushort* dDi_bf  = allocH((size_t)128 * kDi);
    ushort* tb_bf   = allocH((size_t)128 * kD);
    ushort* o768_bf = allocH((size_t)128 * kD);
    ushort* A2      = allocH((size_t)128 * kKa);   // [x_ao | gelu] concat
    // bf16 weights
    ushort* xpw_bf  = allocH((size_t)kNL * 128 * kDi);
    ushort* dpw_bf  = allocH((size_t)kNL * kDi * 64);
    ushort* powp_bf = allocH((size_t)kD * kDi);
    ushort* qkvw_bf = allocH((size_t)3 * kD * kD);
    ushort* aow_bf  = allocH((size_t)kD * kD);
    ushort* ff1w_bf = allocH((size_t)4 * kD * kD);
    ushort* ff2wT   = allocH((size_t)4 * kD * kD); // transposed [3072][768]
    ushort* piw_bf  = allocH((size_t)kDi * kD);    // setup only (W2 A-operand)
    ushort* B2      = allocH((size_t)kDi * kKa);   // [piw | W2] concat
    ushort* emb_bf  = allocH((size_t)kVp * kD);

    size_t base_end = cur;
    ushort* ipw_all = allocH((size_t)kNL * 2 * kDi * kD);
    ushort* opw_all = allocH((size_t)kNL * kD * kDi);
    bool full = (cur <= ws_size);
    ushort* ipw_stg = nullptr;
    ushort* opw_stg = nullptr;
    if (!full) {
        cur = base_end;
        ipw_stg = allocH((size_t)2 * kDi * kD);
        opw_stg = allocH((size_t)kD * kDi);
        if (cur > ws_size) return;
    }

    auto cvt = [&](const float* s, ushort* d, size_t n) {
        cvt_kernel<<<dim3((unsigned)((n / 4 + 255) / 256)), dim3(256), 0, stream>>>(s, d, (int)n);
    };

    hipMemsetAsync(st, 0, sizeof(float) * (size_t)kNL * kB * kDi * kN, stream);

    cvt_xpw_kernel<<<dim3(2880), dim3(256), 0, stream>>>(xpw, xpw_bf);
    cvt_dpw_kernel<<<dim3(9216), dim3(256), 0, stream>>>(dpw, dpw_bf);
    cvt(powp, powp_bf, (size_t)kD * kDi);
    cvt(qkvw, qkvw_bf, (size_t)3 * kD * kD);
    cvt(aow,  aow_bf,  (size_t)kD * kD);
    cvt(ff1w, ff1w_bf, (size_t)4 * kD * kD);
    cvt(piwp, piw_bf,  (size_t)kDi * kD);
    cvt_ff2T_kernel<<<dim3(9216), dim3(256), 0, stream>>>(ff2w, ff2wT);
    cvt_pi_kernel<<<dim3(4608), dim3(256), 0, stream>>>(piwp, B2);
    pib_kernel<<<dim3(6), dim3(256), 0, stream>>>(piwp, ff2b, bias2);
    // W2 = piw @ ff2w  -> B2 cols 768.. (bf16, ld kKa)
    gemm<64, 64, 0, 0, 0, 2, 3>(piw_bf, kD, ff2wT, kD, nullptr, 0, B2 + kD, kKa, nullptr,
                                nullptr, nullptr, kDi, 4 * kD, kD, stream);
    cvt(embed, emb_bf, (size_t)kV * kD);
    if (full) {
        cvt(ipw, ipw_all, (size_t)kNL * 2 * kDi * kD);
        cvt(opw, opw_all, (size_t)kNL * kD * kDi);
    }

    for (int pass = 0; pass < 2; ++pass) {
        const int* ids = pass ? a_ids : q_ids;
        const int* msk = pass ? a_msk : q_msk;

        embed_kernel<<<dim3(kMtok * kD / 256), dim3(256), 0, stream>>>(ids, msk, embed, h, ssqp);

        for (int l = 0; l < kNL; ++l) {
            const ushort* ipw_l;
            const ushort* opw_l;
            if (full) {
                ipw_l = ipw_all + (size_t)l * 2 * kDi * kD;
                opw_l = opw_all + (size_t)l * kD * kDi;
            } else {
                cvt(ipw + (size_t)l * 2 * kDi * kD, ipw_stg, (size_t)2 * kDi * kD);
                cvt(opw + (size_t)l * kD * kDi, opw_stg, (size_t)kD * kDi);
                ipw_l = ipw_stg;
                opw_l = opw_stg;
            }
            gemm_rms<<<dim3(48, 16), dim3(256), 0, stream>>>(
                h, ssqp, norm_w + (size_t)l * kD, ipw_l, kD, x_bf, zT_b, kMtok, 2 * kDi, kD);
            conv_kernel<<<dim3(kDi / 256, kMtok / 16), dim3(256), 0, stream>>>(
                x_bf, cw + (size_t)l * kDi * kK, cb + (size_t)l * kDi, xc_bf, xcT_b);
            gemm<64, 64, 0, 0, 0, 3, 3>(xc_bf, kDi, xpw_bf + (size_t)l * 128 * kDi, kDi,
                                        nullptr, 0, dtin_bf, 0, bcT,
                                        nullptr, nullptr, kMtok, 128, kDi, stream);
            gemm<64, 64, 1, 1, 0, 4, 3>(dtin_bf, 64, dpw_bf + (size_t)l * kDi * 64, 64,
                                        nullptr, 0, nullptr, 0, (float*)dltT_b,
                                        dpb + (size_t)l * kDi, nullptr, kMtok, kDi, 64, stream);
            scan_kernel<<<dim3(kB * kDi * kN / 256), dim3(256), 0, stream>>>(
                dltT_b, xcT_b, zT_b, bcT, alog + (size_t)l * kDi * kN, dpp + (size_t)l * kDi,
                st + (size_t)l * kB * kDi * kN, yb_bf);
            if (!(pass == 0 && l == kNL - 1)) {
                gemm<64, 64, 0, 0, 1, 0, 3, 1>(yb_bf, kDi, opw_l, kDi, h, kD, nullptr, 0, ssqp,
                                               nullptr, nullptr, kMtok, kD, kDi, stream);
            }
        }

        if (pass == 0) {
            contract_kernel<<<dim3(kMref * kDi / 256), dim3(256), 0, stream>>>(st, Cwp, dDi_bf);
            for (int it = 0; it < 12; ++it) {
                gemm<64, 64, 0, 0, 0, 0, 3>(dDi_bf, kDi, powp_bf, kDi, x768, kD, nullptr, 0, nullptr,
                                            nullptr, nullptr, kMref, kD, kDi, stream);
                ln_kernel<<<dim3(kMref), dim3(256), 0, stream>>>(x768, ln1w, ln1b, tb_bf);
                gemm<64, 64, 1, 0, 0, 0, 3>(tb_bf, kD, qkvw_bf, kD, qkvB, 3 * kD, nullptr, 0, nullptr,
                                            qkvbi, nullptr, kMref, 3 * kD, kD, stream);
                attn_kernel<<<dim3(kB * kNH), dim3(32), 0, stream>>>(qkvB, o768_bf);
                gemm<64, 64, 1, 0, 1, 1, 3>(o768_bf, kD, aow_bf, kD, x768, kD, A2, kKa, nullptr,
                                            aob, nullptr, kMref, kD, kD, stream);
                ln_kernel<<<dim3(kMref), dim3(256), 0, stream>>>(x768, ln2w, ln2b, tb_bf);
                gemm<64, 64, 1, 2, 0, 2, 3>(tb_bf, kD, ff1w_bf, kD, nullptr, 0, A2 + kD, kKa, nullptr,
                                            ff1b, nullptr, kMref, 4 * kD, kD, stream);
                gemm<64, 64, 1, 0, 0, 7, 3>(A2, kKa, B2, kKa, nullptr, 0, dDi_bf, kDi, st,
                                            bias2, Cwp, kMref, kDi, kKa, stream, Bwp);
            }
        } else {
            rms_kernel<<<dim3(kMtok), dim3(256), 0, stream>>>(h, norm_f, xin_bf);
            gemm<128, 128, 0, 0, 0, 0, 2, 0, 1>(xin_bf, kD, emb_bf, kD, (float*)d_out, kV,
                                                nullptr, 0, nullptr,
                                                nullptr, nullptr, kMtok, kV, kD, stream);
        }
    }
}